// Round 7
// baseline (234.532 us; speedup 1.0000x reference)
//
#include <hip/hip_runtime.h>

// Alias-free activation: up×2 (K=12 kaiser-sinc) -> lrelu(0.1) -> down×2.
// x: (8,128,32768) fp32; filters: 12 fp32 each; out: (8,128,32768) fp32.
//
// Direct form (verified vs reference R0-R5, absmax 1.6e-2):
//   a[e]   = lrelu(up(2t-5+e)) / 2    (lrelu pos-homogeneous: 2x deferred)
//   a[2i], a[2i+1] share window taps: both read xc[t-5+i+j] = xv[i+3+j]
//   out[t+m] = 2 * sum_k fd[k] * a[2m+k]
// where xc = edge-clamped x, xv[m] = xc[t-8+m] (24 floats, 6x dwordx4).
//
// R1: dropped LDS (R0: 1.9e7 bank-conflict cycles). 100 -> ~76 us.
// R2: nt-stores REGRESSION (WRITE 128->333MB partial-line leak). Reverted.
// R4: OPT=16 = 90 us (halved wave count; VALU 28%/HBM 28%/Occ 41%).
// R5: OPT=4 + 2-tile/wave = ~76 us, neutral: higher FMA redundancy/output
//     + no steady state (wave = 90% prologue). Latency still unhidden.
// R6: OPT=8, 4 consecutive tiles/block, 2-deep A/B register pipeline,
//     fully unrolled: ld0;ld1;comp0;ld2;comp1;ld3;comp2;comp3. Each tile's
//     ~620cyc FMA covers the next tile's ~700cyc load latency.

#define LROW  32768
#define OPT   8
#define BLOCK 256
#define TILE  (OPT * BLOCK)      // 2048 outputs per tile
#define NIT   4                  // tiles per block (consecutive)
#define GX    (LROW / (TILE * NIT))   // 4 blocks in x
#define KS    12
#define SLOPE 0.1f

typedef float f32x4 __attribute__((ext_vector_type(4)));

__device__ __forceinline__ void load_win(float xv[24], const float* __restrict__ xrow, int t)
{
    const int base = t - 8;                    // t%8==0 -> 32B aligned
    if (base >= 0 && base + 24 <= LROW) {
        const f32x4* __restrict__ src = reinterpret_cast<const f32x4*>(xrow + base);
#pragma unroll
        for (int q = 0; q < 6; ++q) {
            f32x4 w = src[q];
            xv[4*q+0] = w.x; xv[4*q+1] = w.y; xv[4*q+2] = w.z; xv[4*q+3] = w.w;
        }
    } else {
        // Only the global first/last thread of each row takes this path.
#pragma unroll
        for (int m = 0; m < 24; ++m) {
            int g = base + m;
            g = g < 0 ? 0 : (g >= LROW ? LROW - 1 : g);
            xv[m] = xrow[g];
        }
    }
}

__device__ __forceinline__ void compute_store(const float xv[24],
                                              const float fu[KS], const float fd[KS],
                                              float* __restrict__ orow, int t)
{
    // 26 act values: a[e] = lrelu(up(2t-5+e))/2, e in [0,26).
    // Pair (a[2i], a[2i+1]) shares the 6-tap window xv[i+3 .. i+8].
    float a[26];
#pragma unroll
    for (int i = 0; i < 13; ++i) {
        float vo = 0.0f, ve = 0.0f;
#pragma unroll
        for (int j = 0; j < 6; ++j) {
            const float xx = xv[i + 3 + j];
            vo = fmaf(fu[2*j + 1], xx, vo);    // a[2i]   (odd up-sample)
            ve = fmaf(fu[2*j],     xx, ve);    // a[2i+1] (even up-sample)
        }
        a[2*i]     = fmaxf(vo, SLOPE * vo);    // lrelu, slope<1
        a[2*i + 1] = fmaxf(ve, SLOPE * ve);
    }

    // Edge replication (reference edge-pads act before the down-conv).
    if (t == 0) {
        a[0] = a[5]; a[1] = a[5]; a[2] = a[5]; a[3] = a[5]; a[4] = a[5];
    }
    if (t == LROW - OPT) {
        a[21] = a[20]; a[22] = a[20]; a[23] = a[20]; a[24] = a[20]; a[25] = a[20];
    }

    // Downsample; fold the deferred 2x here (inline-const v_mul).
    float o[OPT];
#pragma unroll
    for (int m = 0; m < OPT; ++m) {
        float acc = 0.0f;
#pragma unroll
        for (int k = 0; k < KS; ++k) acc = fmaf(fd[k], a[2*m + k], acc);
        o[m] = 2.0f * acc;
    }
    f32x4* po = reinterpret_cast<f32x4*>(orow + t);     // t%8==0 -> aligned
    po[0] = (f32x4){ o[0], o[1], o[2], o[3] };
    po[1] = (f32x4){ o[4], o[5], o[6], o[7] };
}

__global__ __launch_bounds__(BLOCK) void aa_act_kernel(
    const float* __restrict__ x,
    const float* __restrict__ upf,
    const float* __restrict__ dnf,
    float* __restrict__ out)
{
    const int tid = threadIdx.x;
    const size_t row = blockIdx.y;
    const float* __restrict__ xrow = x + row * (size_t)LROW;
    float* __restrict__ orow       = out + row * (size_t)LROW;

    // Raw filter taps: uniform constant-offset reads -> s_load -> SGPR
    // FMA operands (no VGPR cost).
    float fu[KS], fd[KS];
#pragma unroll
    for (int k = 0; k < KS; ++k) { fu[k] = upf[k]; fd[k] = dnf[k]; }

    // 4 consecutive tiles per block; 2-deep A/B register pipeline.
    const int t0 = blockIdx.x * (NIT * TILE) + OPT * tid;

    float xvA[24], xvB[24];
    load_win(xvA, xrow, t0 + 0 * TILE);
    load_win(xvB, xrow, t0 + 1 * TILE);
    compute_store(xvA, fu, fd, orow, t0 + 0 * TILE);
    load_win(xvA, xrow, t0 + 2 * TILE);
    compute_store(xvB, fu, fd, orow, t0 + 1 * TILE);
    load_win(xvB, xrow, t0 + 3 * TILE);
    compute_store(xvA, fu, fd, orow, t0 + 2 * TILE);
    compute_store(xvB, fu, fd, orow, t0 + 3 * TILE);
}

extern "C" void kernel_launch(void* const* d_in, const int* in_sizes, int n_in,
                              void* d_out, int out_size, void* d_ws, size_t ws_size,
                              hipStream_t stream) {
    const float* x   = (const float*)d_in[0];
    const float* upf = (const float*)d_in[1];
    const float* dnf = (const float*)d_in[2];
    float* out = (float*)d_out;

    const int rows = in_sizes[0] / LROW;          // 8*128 = 1024
    dim3 grid(GX, rows);                           // (4, 1024)
    aa_act_kernel<<<grid, dim3(BLOCK), 0, stream>>>(x, upf, dnf, out);
}